// Round 6
// baseline (50747.162 us; speedup 1.0000x reference)
//
#include <hip/hip_runtime.h>
#include <stdint.h>

// Seq2Seq decoder (2-layer LSTM + Luong attention), B=64, T=256, S=512, H=512.
// Round 6: R5 design (1024 thr/WG, 16 waves, 5 barriers/step, weights in LDS,
// T4 activation layout, all-f32) with the part_ctx stride bug FIXED:
//   R5 wrote part_ctx at sg*262144 (4x overscale) -> clobbered cnt/gen -> hang.
//   Correct plane stride is 65536 floats ([256][64][4] per s-group).

typedef float f32x4 __attribute__((ext_vector_type(4)));

#define NWG  256
#define NTHR 1024

// LDS float offsets
#define OFF_W1 0        // 8 x 1536
#define OFF_W2 12288    // 8 x 1024
#define OFF_WM 20480    // 4 x 512
#define OFF_WA 22528    // 2 x 1536
#define OFF_ZB 25600    // 8192 floats (zbuf / cpart)
#define OFF_ML 33792    // 32 floats
#define OFF_ZS 33824    // 512 floats
#define SMEM_F 34336    // 137,344 B

struct Params {
  const float* tgtT4;   // [256][128][64][4]
  const float* mask;    // [64][512]
  const float* b1;      // [2048]
  const float* b2;      // [2048]
  const float* Wm;      // [1024][512] raw (rows = q-col weights)
  const float* enc;     // [64][512][1024] raw f32
  const float* W1T;     // [2048][1536]
  const float* W2T;     // [2048][1024]
  const float* WaT;     // [512][1536]
  float *h1a,*h1b,*h2a,*h2b;   // T4 [128][64][4]
  float *attnT4;               // T4 [128][64][4]
  float *q;                    // [64][1024]
  float *c1,*c2;               // [64][512]
  float *part_ctx;             // [4][256][64][4]  sg-major ctx partials
  float *part_ml;              // [64][4][2]  (M,L) per (b, sg)
  unsigned *cnt,*gen;
  float *out;                  // [64][256][512]
};

__device__ __forceinline__ float sigmf(float x){ return 1.f/(1.f+__expf(-x)); }

// -------- grid barrier (device scope; 256 WGs, 1/CU, co-resident) --------
__device__ void gbar(unsigned* cnt, unsigned* gen){
  __syncthreads();
  if (threadIdx.x == 0){
    unsigned g = __hip_atomic_load(gen, __ATOMIC_RELAXED, __HIP_MEMORY_SCOPE_AGENT);
    unsigned a = __hip_atomic_fetch_add(cnt, 1u, __ATOMIC_ACQ_REL, __HIP_MEMORY_SCOPE_AGENT) + 1u;
    if (a == NWG){
      __hip_atomic_store(cnt, 0u, __ATOMIC_RELAXED, __HIP_MEMORY_SCOPE_AGENT);
      __hip_atomic_fetch_add(gen, 1u, __ATOMIC_RELEASE, __HIP_MEMORY_SCOPE_AGENT);
    } else {
      while (__hip_atomic_load(gen, __ATOMIC_ACQUIRE, __HIP_MEMORY_SCOPE_AGENT) == g)
        __builtin_amdgcn_s_sleep(2);
    }
  }
  __syncthreads();
}

// -------- GEMM core: out[c][b] += sum_k act[k][b] * wL[c][k] --------
// lane = b; wave wv owns kg in [wv*KGW, (wv+1)*KGW); seg select on kg>>7.
// seg pointers pre-offset so addr = seg + kg*256 + lane*4 works with GLOBAL kg.
template<int NCOLS, int KGW>
__device__ __forceinline__ void mm_core(const float* seg0, const float* seg1, const float* seg2,
                                        const float* wL, float* zb, int lane, int wv){
  float acc[NCOLS];
  #pragma unroll
  for (int c=0;c<NCOLS;++c) acc[c]=0.f;
  const int kg0 = wv*KGW;
  #pragma unroll 4
  for (int i=0;i<KGW;++i){
    const int kg = kg0 + i;
    const float* bp = (kg<128) ? seg0 : ((kg<256) ? seg1 : seg2);
    f32x4 a = *(const f32x4*)(bp + ((size_t)kg<<8) + (lane<<2));
    #pragma unroll
    for (int c=0;c<NCOLS;++c){
      f32x4 w = *(const f32x4*)(wL + c*(KGW*64) + (kg<<2));
      acc[c] = fmaf(a[0],w[0],acc[c]); acc[c] = fmaf(a[1],w[1],acc[c]);
      acc[c] = fmaf(a[2],w[2],acc[c]); acc[c] = fmaf(a[3],w[3],acc[c]);
    }
  }
  #pragma unroll
  for (int c=0;c<NCOLS;++c) zb[(wv*NCOLS+c)*64 + lane] = acc[c];
}

// -------- phases A/B: LSTM layers --------
template<int PHASE>
__device__ void lstm_phase(const Params& P, int t, int rp, float* smem){
  const int wg=blockIdx.x, tid=threadIdx.x, lane=tid&63, wv=tid>>6;
  const float* h1r = rp ? P.h1b : P.h1a;
  float*       h1w = rp ? P.h1a : P.h1b;
  const float* h2r = rp ? P.h2b : P.h2a;
  float*       h2w = rp ? P.h2a : P.h2b;

  if (PHASE==1){
    const float* seg0 = P.tgtT4 + ((size_t)t<<15);
    const float* seg1 = P.attnT4 - 32768;
    const float* seg2 = h1r - 65536;
    mm_core<8,24>(seg0, seg1, seg2, smem+OFF_W1, smem+OFF_ZB, lane, wv);
  } else {
    const float* seg0 = h1w;               // h1 NEW
    const float* seg1 = h2r - 32768;       // h2 old
    mm_core<8,16>(seg0, seg1, seg1, smem+OFF_W2, smem+OFF_ZB, lane, wv);
  }
  __syncthreads();
  // 16-partial reduce: 512 threads -> zs[8][64]
  if (tid < 512){
    const int gc = tid>>6, b = tid&63;
    const float* zb = smem+OFF_ZB;
    float s = 0.f;
    #pragma unroll
    for (int w=0; w<16; ++w) s += zb[(w*8+gc)*64 + b];
    smem[OFF_ZS + gc*64 + b] = s;
  }
  __syncthreads();
  if (tid < 128){
    const int b = tid&63, j = tid>>6;
    const int h = (wg<<1)+j;
    const float* bias = (PHASE==1) ? P.b1 : P.b2;
    float z[4];
    #pragma unroll
    for (int g=0; g<4; ++g) z[g] = smem[OFF_ZS + (g*2+j)*64 + b] + bias[(g<<9)+h];
    float* cb = (PHASE==1) ? P.c1 : P.c2;
    float* hw = (PHASE==1) ? h1w  : h2w;
    const int ci = (b<<9)+h;
    float co = cb[ci];
    float cn = sigmf(z[1])*co + sigmf(z[0])*tanhf(z[2]);   // i,f,j,o
    float hn = sigmf(z[3])*tanhf(cn);
    cb[ci] = cn;
    hw[((h>>2)<<8) + (b<<2) + (h&3)] = hn;
  }
}

// -------- phase C: q = h2new @ Wm^T --------
__device__ void qproj_phase(const Params& P, int rp, float* smem){
  const int wg=blockIdx.x, tid=threadIdx.x, lane=tid&63, wv=tid>>6;
  const float* h2n = rp ? P.h2a : P.h2b;
  mm_core<4,8>(h2n, h2n, h2n, smem+OFF_WM, smem+OFF_ZB, lane, wv);
  __syncthreads();
  if (tid < 256){
    const int b = tid&63, j = tid>>6;
    const float* zb = smem+OFF_ZB;
    float s = 0.f;
    #pragma unroll
    for (int w=0; w<16; ++w) s += zb[(w*4+j)*64 + b];
    P.q[(b<<10) + (wg<<2) + j] = s;
  }
}

// -------- phase D: flash attention; WG(b,sg); 16 waves x 8 s-rows --------
__device__ void attn_phase(const Params& P, float* smem){
  const int wg=blockIdx.x, tid=threadIdx.x, lane=tid&63, wv=tid>>6;
  const int b = wg>>2, sg = wg&3;
  float* zb = smem + OFF_ZB;    // [8][1024] partial ctx
  float* ml = smem + OFF_ML;    // [16][2]
  const float* qp = P.q + (b<<10) + (lane<<4);
  f32x4 q0 = *(const f32x4*)qp,     q1 = *(const f32x4*)(qp+4),
        q2 = *(const f32x4*)(qp+8), q3 = *(const f32x4*)(qp+12);
  const int s0 = (sg<<7) + (wv<<3);
  const float* ep = P.enc + ((((size_t)b<<9) + s0)<<10) + (lane<<4);
  const float* mk = P.mask + (b<<9) + s0;
  f32x4 a0,a1,a2,a3, p0,p1,p2,p3;
  a0=*(const f32x4*)ep; a1=*(const f32x4*)(ep+4); a2=*(const f32x4*)(ep+8); a3=*(const f32x4*)(ep+12);
  const float* ep1 = ep + 1024;
  p0=*(const f32x4*)ep1; p1=*(const f32x4*)(ep1+4); p2=*(const f32x4*)(ep1+8); p3=*(const f32x4*)(ep1+12);
  float m = -1e30f, l = 0.f;
  f32x4 cx0={0,0,0,0}, cx1={0,0,0,0}, cx2={0,0,0,0}, cx3={0,0,0,0};
  for (int i=0;i<8;++i){
    f32x4 e0=a0, e1=a1, e2=a2, e3=a3;
    a0=p0; a1=p1; a2=p2; a3=p3;
    if (i<6){
      const float* ep2 = ep + (size_t)(i+2)*1024;
      p0=*(const f32x4*)ep2; p1=*(const f32x4*)(ep2+4); p2=*(const f32x4*)(ep2+8); p3=*(const f32x4*)(ep2+12);
    }
    float d = 0.f;
    #pragma unroll
    for (int j=0;j<4;++j){
      d = fmaf(e0[j],q0[j],d); d = fmaf(e1[j],q1[j],d);
      d = fmaf(e2[j],q2[j],d); d = fmaf(e3[j],q3[j],d);
    }
    d += __shfl_xor(d,1,64);  d += __shfl_xor(d,2,64);  d += __shfl_xor(d,4,64);
    d += __shfl_xor(d,8,64);  d += __shfl_xor(d,16,64); d += __shfl_xor(d,32,64);
    float sc = d + mk[i]*(-1e9f);
    float mn = fmaxf(m, sc);
    float fs = __expf(m - mn), e_ = __expf(sc - mn);
    l = l*fs + e_;
    #pragma unroll
    for (int j=0;j<4;++j){
      cx0[j] = cx0[j]*fs + e_*e0[j]; cx1[j] = cx1[j]*fs + e_*e1[j];
      cx2[j] = cx2[j]*fs + e_*e2[j]; cx3[j] = cx3[j]*fs + e_*e3[j];
    }
    m = mn;
  }
  if (wv < 8){
    float* cp = zb + (wv<<10) + (lane<<4);
    *(f32x4*)cp = cx0; *(f32x4*)(cp+4)=cx1; *(f32x4*)(cp+8)=cx2; *(f32x4*)(cp+12)=cx3;
  }
  if (lane==0){ ml[wv*2]=m; ml[wv*2+1]=l; }
  __syncthreads();
  if (wv >= 8){
    float M = -1e30f;
    #pragma unroll
    for (int w=0;w<16;++w) M = fmaxf(M, ml[w*2]);
    const float ewj = __expf(ml[(wv-8)*2]-M);
    const float ewo = __expf(ml[wv*2]-M);
    float* cp = zb + ((wv-8)<<10) + (lane<<4);
    f32x4 r0=*(f32x4*)cp, r1=*(f32x4*)(cp+4), r2=*(f32x4*)(cp+8), r3=*(f32x4*)(cp+12);
    #pragma unroll
    for (int j=0;j<4;++j){
      r0[j] = ewj*r0[j] + ewo*cx0[j]; r1[j] = ewj*r1[j] + ewo*cx1[j];
      r2[j] = ewj*r2[j] + ewo*cx2[j]; r3[j] = ewj*r3[j] + ewo*cx3[j];
    }
    *(f32x4*)cp = r0; *(f32x4*)(cp+4)=r1; *(f32x4*)(cp+8)=r2; *(f32x4*)(cp+12)=r3;
    if (wv==8 && lane==0){
      float L = 0.f;
      #pragma unroll
      for (int w=0;w<16;++w) L += __expf(ml[w*2]-M)*ml[w*2+1];
      P.part_ml[b*8 + sg*2]   = M;
      P.part_ml[b*8 + sg*2+1] = L;
    }
  }
  __syncthreads();
  // stage 3: 1024 threads, dim k = tid; plane stride 65536 floats (FIXED)
  float c = 0.f;
  #pragma unroll
  for (int j=0;j<8;++j) c += zb[(j<<10)+tid];
  P.part_ctx[((size_t)sg<<16) + ((tid>>2)<<8) + (b<<2) + (tid&3)] = c;
}

// -------- phase E: attn = [h2new, ctx] @ Wa; ctx combined inline --------
__device__ void out_phase(const Params& P, int t, int rp, float* smem){
  const int wg=blockIdx.x, tid=threadIdx.x, lane=tid&63, wv=tid>>6;
  const float* h2n = rp ? P.h2a : P.h2b;
  // per-thread softmax combine weights for b = lane
  f32x4 mlv0 = *(const f32x4*)(P.part_ml + lane*8);
  f32x4 mlv1 = *(const f32x4*)(P.part_ml + lane*8 + 4);
  float M0=mlv0[0], L0=mlv0[1], M1=mlv0[2], L1=mlv0[3];
  float M2=mlv1[0], L2=mlv1[1], M3=mlv1[2], L3=mlv1[3];
  float M = fmaxf(fmaxf(M0,M1), fmaxf(M2,M3));
  float w0=__expf(M0-M), w1=__expf(M1-M), w2=__expf(M2-M), w3=__expf(M3-M);
  float inv = 1.f/(w0*L0 + w1*L1 + w2*L2 + w3*L3);
  w0*=inv; w1*=inv; w2*=inv; w3*=inv;

  const float* wL = smem + OFF_WA;
  float* zb = smem + OFF_ZB;
  float acc0=0.f, acc1=0.f;
  const int kg0 = wv*24;
  #pragma unroll 4
  for (int i=0;i<24;++i){
    const int kg = kg0 + i;
    f32x4 a;
    if (kg < 128){
      a = *(const f32x4*)(h2n + ((size_t)kg<<8) + (lane<<2));
    } else {
      const float* pc = P.part_ctx + (((size_t)kg-128)<<8) + (lane<<2);
      f32x4 g0 = *(const f32x4*)pc;
      f32x4 g1 = *(const f32x4*)(pc + 65536);
      f32x4 g2 = *(const f32x4*)(pc + 131072);
      f32x4 g3 = *(const f32x4*)(pc + 196608);
      #pragma unroll
      for (int j=0;j<4;++j) a[j] = w0*g0[j] + w1*g1[j] + w2*g2[j] + w3*g3[j];
    }
    f32x4 u0 = *(const f32x4*)(wL + 0*1536 + (kg<<2));
    f32x4 u1 = *(const f32x4*)(wL + 1*1536 + (kg<<2));
    acc0 = fmaf(a[0],u0[0],acc0); acc0 = fmaf(a[1],u0[1],acc0);
    acc0 = fmaf(a[2],u0[2],acc0); acc0 = fmaf(a[3],u0[3],acc0);
    acc1 = fmaf(a[0],u1[0],acc1); acc1 = fmaf(a[1],u1[1],acc1);
    acc1 = fmaf(a[2],u1[2],acc1); acc1 = fmaf(a[3],u1[3],acc1);
  }
  zb[(wv*2+0)*64 + lane] = acc0;
  zb[(wv*2+1)*64 + lane] = acc1;
  __syncthreads();
  if (tid < 128){
    const int b = tid&63, j = tid>>6;
    float s = 0.f;
    #pragma unroll
    for (int w=0;w<16;++w) s += zb[(w*2+j)*64 + b];
    const int n = (wg<<1)+j;
    P.out[(((size_t)b<<8) + t)*512 + n] = s;
    P.attnT4[((n>>2)<<8) + (b<<2) + (n&3)] = s;
  }
}

// -------- one-time: weights -> LDS --------
__device__ void load_weights(const Params& P, float* smem){
  const int wg=blockIdx.x, tid=threadIdx.x;
  #pragma unroll
  for (int c=0;c<8;++c){
    const int n = ((c>>1)<<9) + (wg<<1) + (c&1);
    const float* src = P.W1T + (size_t)n*1536;
    float* dst = smem + OFF_W1 + c*1536;
    for (int i=tid;i<1536;i+=NTHR) dst[i]=src[i];
  }
  #pragma unroll
  for (int c=0;c<8;++c){
    const int n = ((c>>1)<<9) + (wg<<1) + (c&1);
    const float* src = P.W2T + (size_t)n*1024;
    float* dst = smem + OFF_W2 + c*1024;
    for (int i=tid;i<1024;i+=NTHR) dst[i]=src[i];
  }
  #pragma unroll
  for (int c=0;c<4;++c){
    const int n = (wg<<2)+c;
    const float* src = P.Wm + (size_t)n*512;
    float* dst = smem + OFF_WM + c*512;
    for (int i=tid;i<512;i+=NTHR) dst[i]=src[i];
  }
  #pragma unroll
  for (int c=0;c<2;++c){
    const int n = (wg<<1)+c;
    const float* src = P.WaT + (size_t)n*1536;
    float* dst = smem + OFF_WA + c*1536;
    for (int i=tid;i<1536;i+=NTHR) dst[i]=src[i];
  }
  __syncthreads();
}

// -------- main persistent kernel --------
__global__ __launch_bounds__(NTHR)
void seq_main(Params P){
  __shared__ float smem[SMEM_F];
  load_weights(P, smem);
  #pragma clang loop unroll(disable)
  for (int t=0; t<256; ++t){
    const int rp = t&1;
    lstm_phase<1>(P, t, rp, smem);  gbar(P.cnt,P.gen);
    lstm_phase<2>(P, t, rp, smem);  gbar(P.cnt,P.gen);
    qproj_phase(P, rp, smem);       gbar(P.cnt,P.gen);
    attn_phase(P, smem);            gbar(P.cnt,P.gen);
    out_phase(P, t, rp, smem);      gbar(P.cnt,P.gen);
  }
}

// ======== prep kernels ========
// dst[n*K + k] = src(k,n), src(k,n) = k<KA ? a[k*N+n] : b[(k-KA)*N+n]
__global__ void transT(const float* a, const float* bsrc, float* dst, int K, int N, int KA){
  __shared__ float tile[32][33];
  const int ntk = K>>5;
  const int tn = blockIdx.x / ntk, tk = blockIdx.x - tn*ntk;
  const int tid = threadIdx.x;
  const int c = tid & 31, r = tid >> 5;
  for (int rr=r; rr<32; rr+=8){
    const int k = (tk<<5)+rr, n = (tn<<5)+c;
    tile[rr][c] = (k<KA) ? a[(size_t)k*N+n] : bsrc[(size_t)(k-KA)*N+n];
  }
  __syncthreads();
  for (int rr=r; rr<32; rr+=8){
    const int n = (tn<<5)+rr, k = (tk<<5)+c;
    dst[(size_t)n*K + k] = tile[c][rr];
  }
}

// tgt[b][t][k] -> tgtT4[t][k>>2][b][k&3]
__global__ void prep_tgt(const float* tgt, float* tgtT4){
  __shared__ float xt[64*517];
  const int t = blockIdx.x, tid = threadIdx.x;   // 256 threads
  for (int i=tid; i<64*512; i+=256){
    const int bb = i>>9, k = i&511;
    xt[bb*517 + k] = tgt[((size_t)bb*256 + t)*512 + k];
  }
  __syncthreads();
  for (int i=tid; i<128*64; i+=256){
    const int kg = i>>6, bb = i&63;
    f32x4 v = { xt[bb*517 + kg*4], xt[bb*517 + kg*4 + 1],
                xt[bb*517 + kg*4 + 2], xt[bb*517 + kg*4 + 3] };
    *(f32x4*)(tgtT4 + ((size_t)t<<15) + (kg<<8) + (bb<<2)) = v;
  }
}

__global__ void init_state(const float* fwh, const float* fwc, const float* bwh, const float* bwc,
                           float* h1a, float* h2a, float* attnT4, float* c1, float* c2,
                           unsigned* cnt, unsigned* gen){
  const int i = blockIdx.x*blockDim.x + threadIdx.x;
  if (i < 64*512){
    const int bb = i>>9, k = i&511;
    const int t4 = ((k>>2)<<8) + (bb<<2) + (k&3);
    h1a[t4] = fwh[i];
    h2a[t4] = bwh[i];
    attnT4[t4] = 0.f;
    c1[i] = fwc[i];
    c2[i] = bwc[i];
  }
  if (i == 0){ *cnt = 0u; *gen = 0u; }
}

extern "C" void kernel_launch(void* const* d_in, const int* in_sizes, int n_in,
                              void* d_out, int out_size, void* d_ws, size_t ws_size,
                              hipStream_t stream){
  if (n_in < 15) return;
  const float* tgt = (const float*)d_in[0];
  const float* fwh = (const float*)d_in[1];
  const float* fwc = (const float*)d_in[2];
  const float* bwh = (const float*)d_in[3];
  const float* bwc = (const float*)d_in[4];
  const float* enc = (const float*)d_in[5];
  const float* msk = (const float*)d_in[6];
  const float* Wm  = (const float*)d_in[7];
  const float* Wa  = (const float*)d_in[8];
  const float* ki1 = (const float*)d_in[9];
  const float* kr1 = (const float*)d_in[10];
  const float* b1  = (const float*)d_in[11];
  const float* ki2 = (const float*)d_in[12];
  const float* kr2 = (const float*)d_in[13];
  const float* b2  = (const float*)d_in[14];

  char* w = (char*)d_ws;
  size_t o = 0;
  auto carve = [&](size_t bytes)->char*{
    char* r = w + o; o = (o + bytes + 255) & ~(size_t)255; return r;
  };
  float* W1T    = (float*)carve(2048ull*1536*4);
  float* W2T    = (float*)carve(2048ull*1024*4);
  float* WaT    = (float*)carve(512ull*1536*4);
  float* tgtT4  = (float*)carve(256ull*128*256*4);
  float* h1a    = (float*)carve(128ull*256*4);
  float* h1b    = (float*)carve(128ull*256*4);
  float* h2a    = (float*)carve(128ull*256*4);
  float* h2b    = (float*)carve(128ull*256*4);
  float* attnT4 = (float*)carve(128ull*256*4);
  float* q      = (float*)carve(64ull*1024*4);
  float* c1     = (float*)carve(64ull*512*4);
  float* c2     = (float*)carve(64ull*512*4);
  float* part_ctx = (float*)carve(4ull*256*256*4);
  float* part_ml  = (float*)carve(64ull*8*4);
  unsigned* cnt = (unsigned*)carve(128);
  unsigned* gen = (unsigned*)carve(128);
  if (o > ws_size) return;   // ~61 MB needed

  hipLaunchKernelGGL(transT, dim3(64*48), dim3(256), 0, stream, ki1, kr1, W1T, 1536, 2048, 1024);
  hipLaunchKernelGGL(transT, dim3(64*32), dim3(256), 0, stream, ki2, kr2, W2T, 1024, 2048, 512);
  hipLaunchKernelGGL(transT, dim3(16*48), dim3(256), 0, stream, Wa,  Wa,  WaT, 1536, 512, 1536);
  hipLaunchKernelGGL(prep_tgt, dim3(256), dim3(256), 0, stream, tgt, tgtT4);
  hipLaunchKernelGGL(init_state, dim3(128), dim3(256), 0, stream,
                     fwh, fwc, bwh, bwc, h1a, h2a, attnT4, c1, c2, cnt, gen);

  Params P;
  P.tgtT4 = tgtT4; P.mask = msk; P.b1 = b1; P.b2 = b2;
  P.Wm = Wm; P.enc = enc;
  P.W1T = W1T; P.W2T = W2T; P.WaT = WaT;
  P.h1a = h1a; P.h1b = h1b; P.h2a = h2a; P.h2b = h2b;
  P.attnT4 = attnT4; P.q = q;
  P.c1 = c1; P.c2 = c2;
  P.part_ctx = part_ctx; P.part_ml = part_ml;
  P.cnt = cnt; P.gen = gen;
  P.out = (float*)d_out;

  hipLaunchKernelGGL(seq_main, dim3(NWG), dim3(NTHR), 0, stream, P);
}

// Round 7
// 46059.238 us; speedup vs baseline: 1.1018x; 1.1018x over previous
//
#include <hip/hip_runtime.h>
#include <stdint.h>

// Seq2Seq decoder (2-layer LSTM + Luong attention), B=64, T=256, S=512, H=512.
// Round 7: enc RESIDENT IN REGISTERS (128 VGPR/thread holds this WG's 128
// s-rows x 1024 slice) -> phase D has ZERO global traffic. Mask preloaded too.
// __launch_bounds__(1024, 4) -> 512-VGPR cap, kills R6's scratch spills
// (R6: VGPR capped 64 -> 8.5 GB spill writes, L3 thrash, 50.7ms).
// Everything else = R6 (1024 thr, 5 barriers/step, weights in LDS, T4 acts, f32).

typedef float f32x4 __attribute__((ext_vector_type(4)));

#define NWG  256
#define NTHR 1024

// LDS float offsets
#define OFF_W1 0        // 8 x 1536
#define OFF_W2 12288    // 8 x 1024
#define OFF_WM 20480    // 4 x 512
#define OFF_WA 22528    // 2 x 1536
#define OFF_ZB 25600    // 8192 floats (zbuf / cpart)
#define OFF_ML 33792    // 32 floats
#define OFF_ZS 33824    // 512 floats
#define SMEM_F 34336    // 137,344 B

struct Params {
  const float* tgtT4;   // [256][128][64][4]
  const float* mask;    // [64][512]
  const float* b1;      // [2048]
  const float* b2;      // [2048]
  const float* Wm;      // [1024][512] raw (rows = q-col weights)
  const float* enc;     // [64][512][1024] raw f32
  const float* W1T;     // [2048][1536]
  const float* W2T;     // [2048][1024]
  const float* WaT;     // [512][1536]
  float *h1a,*h1b,*h2a,*h2b;   // T4 [128][64][4]
  float *attnT4;               // T4 [128][64][4]
  float *q;                    // [64][1024]
  float *c1,*c2;               // [64][512]
  float *part_ctx;             // [4][256][64][4]  sg-major ctx partials
  float *part_ml;              // [64][4][2]  (M,L) per (b, sg)
  unsigned *cnt,*gen;
  float *out;                  // [64][256][512]
};

__device__ __forceinline__ float sigmf(float x){ return 1.f/(1.f+__expf(-x)); }

// -------- grid barrier (device scope; 256 WGs, 1/CU, co-resident) --------
__device__ void gbar(unsigned* cnt, unsigned* gen){
  __syncthreads();
  if (threadIdx.x == 0){
    unsigned g = __hip_atomic_load(gen, __ATOMIC_RELAXED, __HIP_MEMORY_SCOPE_AGENT);
    unsigned a = __hip_atomic_fetch_add(cnt, 1u, __ATOMIC_ACQ_REL, __HIP_MEMORY_SCOPE_AGENT) + 1u;
    if (a == NWG){
      __hip_atomic_store(cnt, 0u, __ATOMIC_RELAXED, __HIP_MEMORY_SCOPE_AGENT);
      __hip_atomic_fetch_add(gen, 1u, __ATOMIC_RELEASE, __HIP_MEMORY_SCOPE_AGENT);
    } else {
      while (__hip_atomic_load(gen, __ATOMIC_ACQUIRE, __HIP_MEMORY_SCOPE_AGENT) == g)
        __builtin_amdgcn_s_sleep(2);
    }
  }
  __syncthreads();
}

// -------- GEMM core: out[c][b] += sum_k act[k][b] * wL[c][k] --------
template<int NCOLS, int KGW>
__device__ __forceinline__ void mm_core(const float* seg0, const float* seg1, const float* seg2,
                                        const float* wL, float* zb, int lane, int wv){
  float acc[NCOLS];
  #pragma unroll
  for (int c=0;c<NCOLS;++c) acc[c]=0.f;
  const int kg0 = wv*KGW;
  #pragma unroll 4
  for (int i=0;i<KGW;++i){
    const int kg = kg0 + i;
    const float* bp = (kg<128) ? seg0 : ((kg<256) ? seg1 : seg2);
    f32x4 a = *(const f32x4*)(bp + ((size_t)kg<<8) + (lane<<2));
    #pragma unroll
    for (int c=0;c<NCOLS;++c){
      f32x4 w = *(const f32x4*)(wL + c*(KGW*64) + (kg<<2));
      acc[c] = fmaf(a[0],w[0],acc[c]); acc[c] = fmaf(a[1],w[1],acc[c]);
      acc[c] = fmaf(a[2],w[2],acc[c]); acc[c] = fmaf(a[3],w[3],acc[c]);
    }
  }
  #pragma unroll
  for (int c=0;c<NCOLS;++c) zb[(wv*NCOLS+c)*64 + lane] = acc[c];
}

// -------- phases A/B: LSTM layers --------
template<int PHASE>
__device__ void lstm_phase(const Params& P, int t, int rp, float* smem){
  const int wg=blockIdx.x, tid=threadIdx.x, lane=tid&63, wv=tid>>6;
  const float* h1r = rp ? P.h1b : P.h1a;
  float*       h1w = rp ? P.h1a : P.h1b;
  const float* h2r = rp ? P.h2b : P.h2a;
  float*       h2w = rp ? P.h2a : P.h2b;

  if (PHASE==1){
    const float* seg0 = P.tgtT4 + ((size_t)t<<15);
    const float* seg1 = P.attnT4 - 32768;
    const float* seg2 = h1r - 65536;
    mm_core<8,24>(seg0, seg1, seg2, smem+OFF_W1, smem+OFF_ZB, lane, wv);
  } else {
    const float* seg0 = h1w;               // h1 NEW
    const float* seg1 = h2r - 32768;       // h2 old
    mm_core<8,16>(seg0, seg1, seg1, smem+OFF_W2, smem+OFF_ZB, lane, wv);
  }
  __syncthreads();
  // 16-partial reduce: 512 threads -> zs[8][64]
  if (tid < 512){
    const int gc = tid>>6, b = tid&63;
    const float* zb = smem+OFF_ZB;
    float s = 0.f;
    #pragma unroll
    for (int w=0; w<16; ++w) s += zb[(w*8+gc)*64 + b];
    smem[OFF_ZS + gc*64 + b] = s;
  }
  __syncthreads();
  if (tid < 128){
    const int b = tid&63, j = tid>>6;
    const int h = (wg<<1)+j;
    const float* bias = (PHASE==1) ? P.b1 : P.b2;
    float z[4];
    #pragma unroll
    for (int g=0; g<4; ++g) z[g] = smem[OFF_ZS + (g*2+j)*64 + b] + bias[(g<<9)+h];
    float* cb = (PHASE==1) ? P.c1 : P.c2;
    float* hw = (PHASE==1) ? h1w  : h2w;
    const int ci = (b<<9)+h;
    float co = cb[ci];
    float cn = sigmf(z[1])*co + sigmf(z[0])*tanhf(z[2]);   // i,f,j,o
    float hn = sigmf(z[3])*tanhf(cn);
    cb[ci] = cn;
    hw[((h>>2)<<8) + (b<<2) + (h&3)] = hn;
  }
}

// -------- phase C: q = h2new @ Wm^T --------
__device__ void qproj_phase(const Params& P, int rp, float* smem){
  const int wg=blockIdx.x, tid=threadIdx.x, lane=tid&63, wv=tid>>6;
  const float* h2n = rp ? P.h2a : P.h2b;
  mm_core<4,8>(h2n, h2n, h2n, smem+OFF_WM, smem+OFF_ZB, lane, wv);
  __syncthreads();
  if (tid < 256){
    const int b = tid&63, j = tid>>6;
    const float* zb = smem+OFF_ZB;
    float s = 0.f;
    #pragma unroll
    for (int w=0; w<16; ++w) s += zb[(w*4+j)*64 + b];
    P.q[(b<<10) + (wg<<2) + j] = s;
  }
}

// -------- phase D: flash attention from REGISTER-resident enc --------
__device__ void attn_phase(const Params& P, const f32x4 (&er)[8][4], const float* mk,
                           float* smem){
  const int wg=blockIdx.x, tid=threadIdx.x, lane=tid&63, wv=tid>>6;
  const int b = wg>>2, sg = wg&3;
  float* zb = smem + OFF_ZB;    // [8][1024] partial ctx
  float* ml = smem + OFF_ML;    // [16][2]
  const float* qp = P.q + (b<<10) + (lane<<4);
  f32x4 qv[4];
  qv[0] = *(const f32x4*)qp;     qv[1] = *(const f32x4*)(qp+4);
  qv[2] = *(const f32x4*)(qp+8); qv[3] = *(const f32x4*)(qp+12);
  float m = -1e30f, l = 0.f;
  f32x4 cx[4] = {{0,0,0,0},{0,0,0,0},{0,0,0,0},{0,0,0,0}};
  #pragma unroll
  for (int i=0;i<8;++i){
    float d = 0.f;
    #pragma unroll
    for (int jb=0;jb<4;++jb){
      d = fmaf(er[i][jb][0], qv[jb][0], d);
      d = fmaf(er[i][jb][1], qv[jb][1], d);
      d = fmaf(er[i][jb][2], qv[jb][2], d);
      d = fmaf(er[i][jb][3], qv[jb][3], d);
    }
    d += __shfl_xor(d,1,64);  d += __shfl_xor(d,2,64);  d += __shfl_xor(d,4,64);
    d += __shfl_xor(d,8,64);  d += __shfl_xor(d,16,64); d += __shfl_xor(d,32,64);
    float sc = d + mk[i];
    float mn = fmaxf(m, sc);
    float fs = __expf(m - mn), e_ = __expf(sc - mn);
    l = l*fs + e_;
    #pragma unroll
    for (int jb=0;jb<4;++jb){
      #pragma unroll
      for (int j=0;j<4;++j) cx[jb][j] = cx[jb][j]*fs + e_*er[i][jb][j];
    }
    m = mn;
  }
  if (wv < 8){
    float* cp = zb + (wv<<10) + (lane<<4);
    #pragma unroll
    for (int jb=0;jb<4;++jb) *(f32x4*)(cp + jb*4) = cx[jb];
  }
  if (lane==0){ ml[wv*2]=m; ml[wv*2+1]=l; }
  __syncthreads();
  if (wv >= 8){
    float M = -1e30f;
    #pragma unroll
    for (int w=0;w<16;++w) M = fmaxf(M, ml[w*2]);
    const float ewj = __expf(ml[(wv-8)*2]-M);
    const float ewo = __expf(ml[wv*2]-M);
    float* cp = zb + ((wv-8)<<10) + (lane<<4);
    #pragma unroll
    for (int jb=0;jb<4;++jb){
      f32x4 r = *(f32x4*)(cp + jb*4);
      #pragma unroll
      for (int j=0;j<4;++j) r[j] = ewj*r[j] + ewo*cx[jb][j];
      *(f32x4*)(cp + jb*4) = r;
    }
    if (wv==8 && lane==0){
      float L = 0.f;
      #pragma unroll
      for (int w=0;w<16;++w) L += __expf(ml[w*2]-M)*ml[w*2+1];
      P.part_ml[b*8 + sg*2]   = M;
      P.part_ml[b*8 + sg*2+1] = L;
    }
  }
  __syncthreads();
  // stage 3: 1024 threads, dim k = tid; plane stride 65536 floats
  float c = 0.f;
  #pragma unroll
  for (int j=0;j<8;++j) c += zb[(j<<10)+tid];
  P.part_ctx[((size_t)sg<<16) + ((tid>>2)<<8) + (b<<2) + (tid&3)] = c;
}

// -------- phase E: attn = [h2new, ctx] @ Wa; ctx combined inline --------
__device__ void out_phase(const Params& P, int t, int rp, float* smem){
  const int wg=blockIdx.x, tid=threadIdx.x, lane=tid&63, wv=tid>>6;
  const float* h2n = rp ? P.h2a : P.h2b;
  // per-thread softmax combine weights for b = lane
  f32x4 mlv0 = *(const f32x4*)(P.part_ml + lane*8);
  f32x4 mlv1 = *(const f32x4*)(P.part_ml + lane*8 + 4);
  float M0=mlv0[0], L0=mlv0[1], M1=mlv0[2], L1=mlv0[3];
  float M2=mlv1[0], L2=mlv1[1], M3=mlv1[2], L3=mlv1[3];
  float M = fmaxf(fmaxf(M0,M1), fmaxf(M2,M3));
  float w0=__expf(M0-M), w1=__expf(M1-M), w2=__expf(M2-M), w3=__expf(M3-M);
  float inv = 1.f/(w0*L0 + w1*L1 + w2*L2 + w3*L3);
  w0*=inv; w1*=inv; w2*=inv; w3*=inv;

  const float* wL = smem + OFF_WA;
  float* zb = smem + OFF_ZB;
  float acc0=0.f, acc1=0.f;
  const int kg0 = wv*24;
  #pragma unroll 4
  for (int i=0;i<24;++i){
    const int kg = kg0 + i;
    f32x4 a;
    if (kg < 128){
      a = *(const f32x4*)(h2n + ((size_t)kg<<8) + (lane<<2));
    } else {
      const float* pc = P.part_ctx + (((size_t)kg-128)<<8) + (lane<<2);
      f32x4 g0 = *(const f32x4*)pc;
      f32x4 g1 = *(const f32x4*)(pc + 65536);
      f32x4 g2 = *(const f32x4*)(pc + 131072);
      f32x4 g3 = *(const f32x4*)(pc + 196608);
      #pragma unroll
      for (int j=0;j<4;++j) a[j] = w0*g0[j] + w1*g1[j] + w2*g2[j] + w3*g3[j];
    }
    f32x4 u0 = *(const f32x4*)(wL + 0*1536 + (kg<<2));
    f32x4 u1 = *(const f32x4*)(wL + 1*1536 + (kg<<2));
    acc0 = fmaf(a[0],u0[0],acc0); acc0 = fmaf(a[1],u0[1],acc0);
    acc0 = fmaf(a[2],u0[2],acc0); acc0 = fmaf(a[3],u0[3],acc0);
    acc1 = fmaf(a[0],u1[0],acc1); acc1 = fmaf(a[1],u1[1],acc1);
    acc1 = fmaf(a[2],u1[2],acc1); acc1 = fmaf(a[3],u1[3],acc1);
  }
  zb[(wv*2+0)*64 + lane] = acc0;
  zb[(wv*2+1)*64 + lane] = acc1;
  __syncthreads();
  if (tid < 128){
    const int b = tid&63, j = tid>>6;
    float s = 0.f;
    #pragma unroll
    for (int w=0;w<16;++w) s += zb[(w*2+j)*64 + b];
    const int n = (wg<<1)+j;
    P.out[(((size_t)b<<8) + t)*512 + n] = s;
    P.attnT4[((n>>2)<<8) + (b<<2) + (n&3)] = s;
  }
}

// -------- one-time: weights -> LDS --------
__device__ void load_weights(const Params& P, float* smem){
  const int wg=blockIdx.x, tid=threadIdx.x;
  #pragma unroll
  for (int c=0;c<8;++c){
    const int n = ((c>>1)<<9) + (wg<<1) + (c&1);
    const float* src = P.W1T + (size_t)n*1536;
    float* dst = smem + OFF_W1 + c*1536;
    for (int i=tid;i<1536;i+=NTHR) dst[i]=src[i];
  }
  #pragma unroll
  for (int c=0;c<8;++c){
    const int n = ((c>>1)<<9) + (wg<<1) + (c&1);
    const float* src = P.W2T + (size_t)n*1024;
    float* dst = smem + OFF_W2 + c*1024;
    for (int i=tid;i<1024;i+=NTHR) dst[i]=src[i];
  }
  #pragma unroll
  for (int c=0;c<4;++c){
    const int n = (wg<<2)+c;
    const float* src = P.Wm + (size_t)n*512;
    float* dst = smem + OFF_WM + c*512;
    for (int i=tid;i<512;i+=NTHR) dst[i]=src[i];
  }
  #pragma unroll
  for (int c=0;c<2;++c){
    const int n = (wg<<1)+c;
    const float* src = P.WaT + (size_t)n*1536;
    float* dst = smem + OFF_WA + c*1536;
    for (int i=tid;i<1536;i+=NTHR) dst[i]=src[i];
  }
  __syncthreads();
}

// -------- main persistent kernel --------
__global__ __launch_bounds__(NTHR, 4)
void seq_main(Params P){
  __shared__ float smem[SMEM_F];
  load_weights(P, smem);

  // ---- one-time: this thread's enc slice + mask -> REGISTERS ----
  const int tid=threadIdx.x, lane=tid&63, wv=tid>>6, wg=blockIdx.x;
  const int db = wg>>2, sg = wg&3;
  const int s0 = (sg<<7) + (wv<<3);
  f32x4 er[8][4];
  {
    const float* ep = P.enc + ((((size_t)db<<9) + s0)<<10) + (lane<<4);
    #pragma unroll
    for (int i=0;i<8;++i){
      #pragma unroll
      for (int jb=0;jb<4;++jb)
        er[i][jb] = *(const f32x4*)(ep + (size_t)i*1024 + (jb<<2));
    }
  }
  float mk[8];
  #pragma unroll
  for (int i=0;i<8;++i) mk[i] = P.mask[(db<<9) + s0 + i] * (-1e9f);

  #pragma clang loop unroll(disable)
  for (int t=0; t<256; ++t){
    const int rp = t&1;
    lstm_phase<1>(P, t, rp, smem);   gbar(P.cnt,P.gen);
    lstm_phase<2>(P, t, rp, smem);   gbar(P.cnt,P.gen);
    qproj_phase(P, rp, smem);        gbar(P.cnt,P.gen);
    attn_phase(P, er, mk, smem);     gbar(P.cnt,P.gen);
    out_phase(P, t, rp, smem);       gbar(P.cnt,P.gen);
  }
}

// ======== prep kernels ========
// dst[n*K + k] = src(k,n), src(k,n) = k<KA ? a[k*N+n] : b[(k-KA)*N+n]
__global__ void transT(const float* a, const float* bsrc, float* dst, int K, int N, int KA){
  __shared__ float tile[32][33];
  const int ntk = K>>5;
  const int tn = blockIdx.x / ntk, tk = blockIdx.x - tn*ntk;
  const int tid = threadIdx.x;
  const int c = tid & 31, r = tid >> 5;
  for (int rr=r; rr<32; rr+=8){
    const int k = (tk<<5)+rr, n = (tn<<5)+c;
    tile[rr][c] = (k<KA) ? a[(size_t)k*N+n] : bsrc[(size_t)(k-KA)*N+n];
  }
  __syncthreads();
  for (int rr=r; rr<32; rr+=8){
    const int n = (tn<<5)+rr, k = (tk<<5)+c;
    dst[(size_t)n*K + k] = tile[c][rr];
  }
}

// tgt[b][t][k] -> tgtT4[t][k>>2][b][k&3]
__global__ void prep_tgt(const float* tgt, float* tgtT4){
  __shared__ float xt[64*517];
  const int t = blockIdx.x, tid = threadIdx.x;   // 256 threads
  for (int i=tid; i<64*512; i+=256){
    const int bb = i>>9, k = i&511;
    xt[bb*517 + k] = tgt[((size_t)bb*256 + t)*512 + k];
  }
  __syncthreads();
  for (int i=tid; i<128*64; i+=256){
    const int kg = i>>6, bb = i&63;
    f32x4 v = { xt[bb*517 + kg*4], xt[bb*517 + kg*4 + 1],
                xt[bb*517 + kg*4 + 2], xt[bb*517 + kg*4 + 3] };
    *(f32x4*)(tgtT4 + ((size_t)t<<15) + (kg<<8) + (bb<<2)) = v;
  }
}

__global__ void init_state(const float* fwh, const float* fwc, const float* bwh, const float* bwc,
                           float* h1a, float* h2a, float* attnT4, float* c1, float* c2,
                           unsigned* cnt, unsigned* gen){
  const int i = blockIdx.x*blockDim.x + threadIdx.x;
  if (i < 64*512){
    const int bb = i>>9, k = i&511;
    const int t4 = ((k>>2)<<8) + (bb<<2) + (k&3);
    h1a[t4] = fwh[i];
    h2a[t4] = bwh[i];
    attnT4[t4] = 0.f;
    c1[i] = fwc[i];
    c2[i] = bwc[i];
  }
  if (i == 0){ *cnt = 0u; *gen = 0u; }
}

extern "C" void kernel_launch(void* const* d_in, const int* in_sizes, int n_in,
                              void* d_out, int out_size, void* d_ws, size_t ws_size,
                              hipStream_t stream){
  if (n_in < 15) return;
  const float* tgt = (const float*)d_in[0];
  const float* fwh = (const float*)d_in[1];
  const float* fwc = (const float*)d_in[2];
  const float* bwh = (const float*)d_in[3];
  const float* bwc = (const float*)d_in[4];
  const float* enc = (const float*)d_in[5];
  const float* msk = (const float*)d_in[6];
  const float* Wm  = (const float*)d_in[7];
  const float* Wa  = (const float*)d_in[8];
  const float* ki1 = (const float*)d_in[9];
  const float* kr1 = (const float*)d_in[10];
  const float* b1  = (const float*)d_in[11];
  const float* ki2 = (const float*)d_in[12];
  const float* kr2 = (const float*)d_in[13];
  const float* b2  = (const float*)d_in[14];

  char* w = (char*)d_ws;
  size_t o = 0;
  auto carve = [&](size_t bytes)->char*{
    char* r = w + o; o = (o + bytes + 255) & ~(size_t)255; return r;
  };
  float* W1T    = (float*)carve(2048ull*1536*4);
  float* W2T    = (float*)carve(2048ull*1024*4);
  float* WaT    = (float*)carve(512ull*1536*4);
  float* tgtT4  = (float*)carve(256ull*128*256*4);
  float* h1a    = (float*)carve(128ull*256*4);
  float* h1b    = (float*)carve(128ull*256*4);
  float* h2a    = (float*)carve(128ull*256*4);
  float* h2b    = (float*)carve(128ull*256*4);
  float* attnT4 = (float*)carve(128ull*256*4);
  float* q      = (float*)carve(64ull*1024*4);
  float* c1     = (float*)carve(64ull*512*4);
  float* c2     = (float*)carve(64ull*512*4);
  float* part_ctx = (float*)carve(4ull*256*256*4);
  float* part_ml  = (float*)carve(64ull*8*4);
  unsigned* cnt = (unsigned*)carve(128);
  unsigned* gen = (unsigned*)carve(128);
  if (o > ws_size) return;   // ~61 MB needed

  hipLaunchKernelGGL(transT, dim3(64*48), dim3(256), 0, stream, ki1, kr1, W1T, 1536, 2048, 1024);
  hipLaunchKernelGGL(transT, dim3(64*32), dim3(256), 0, stream, ki2, kr2, W2T, 1024, 2048, 512);
  hipLaunchKernelGGL(transT, dim3(16*48), dim3(256), 0, stream, Wa,  Wa,  WaT, 1536, 512, 1536);
  hipLaunchKernelGGL(prep_tgt, dim3(256), dim3(256), 0, stream, tgt, tgtT4);
  hipLaunchKernelGGL(init_state, dim3(128), dim3(256), 0, stream,
                     fwh, fwc, bwh, bwc, h1a, h2a, attnT4, c1, c2, cnt, gen);

  Params P;
  P.tgtT4 = tgtT4; P.mask = msk; P.b1 = b1; P.b2 = b2;
  P.Wm = Wm; P.enc = enc;
  P.W1T = W1T; P.W2T = W2T; P.WaT = WaT;
  P.h1a = h1a; P.h1b = h1b; P.h2a = h2a; P.h2b = h2b;
  P.attnT4 = attnT4; P.q = q;
  P.c1 = c1; P.c2 = c2;
  P.part_ctx = part_ctx; P.part_ml = part_ml;
  P.cnt = cnt; P.gen = gen;
  P.out = (float*)d_out;

  hipLaunchKernelGGL(seq_main, dim3(NWG), dim3(NTHR), 0, stream, P);
}

// Round 8
// 43331.290 us; speedup vs baseline: 1.1711x; 1.0630x over previous
//
#include <hip/hip_runtime.h>
#include <stdint.h>

// Seq2Seq decoder (2-layer LSTM + Luong attention), B=64, T=256, S=512, H=512.
// Round 8: phase D = mask-skip streaming attention.
//  - ~50% of s-rows are masked (weight==0 exactly, underflow) -> skip them.
//    Rows are wave-uniform (wave owns 8 contiguous s) -> no divergence.
//  - 1-row double-buffered enc stream (~80 VGPR, fits 128 budget -> no spills;
//    R7 lesson: 128-reg er array + working set > budget -> scratch thrash).
//  - first row issued BEFORE the grid barrier (latency hides under spin).
//  - hierarchical grid barrier (16 groups x 16 WGs) cuts atomic contention.
// Rest = R6/R7: 1024 thr, 5 barriers/step, weights in LDS, T4 acts, all-f32.

typedef float f32x4 __attribute__((ext_vector_type(4)));

#define NWG  256
#define NTHR 1024

// LDS float offsets
#define OFF_W1 0        // 8 x 1536
#define OFF_W2 12288    // 8 x 1024
#define OFF_WM 20480    // 4 x 512
#define OFF_WA 22528    // 2 x 1536
#define OFF_ZB 25600    // 8192 floats (zbuf / cpart)
#define OFF_ML 33792    // 32 floats
#define OFF_ZS 33824    // 512 floats
#define SMEM_F 34336    // 137,344 B

struct Params {
  const float* tgtT4;   // [256][128][64][4]
  const float* mask;    // [64][512]
  const float* b1;      // [2048]
  const float* b2;      // [2048]
  const float* Wm;      // [1024][512]
  const float* enc;     // [64][512][1024]
  const float* W1T;     // [2048][1536]
  const float* W2T;     // [2048][1024]
  const float* WaT;     // [512][1536]
  float *h1a,*h1b,*h2a,*h2b;   // T4 [128][64][4]
  float *attnT4;               // T4 [128][64][4]
  float *q;                    // [64][1024]
  float *c1,*c2;               // [64][512]
  float *part_ctx;             // [4][256][64][4]
  float *part_ml;              // [64][4][2]
  unsigned *cnts;              // 16 group counters, 64B apart
  unsigned *sup;               // super counter
  unsigned *gen;               // generation
  float *out;                  // [64][256][512]
};

__device__ __forceinline__ float sigmf(float x){ return 1.f/(1.f+__expf(-x)); }

// -------- hierarchical grid barrier (16 groups x 16 WGs) --------
__device__ __forceinline__ void gbar(const Params& P){
  __syncthreads();
  if (threadIdx.x == 0){
    unsigned g = __hip_atomic_load(P.gen, __ATOMIC_RELAXED, __HIP_MEMORY_SCOPE_AGENT);
    const unsigned grp = blockIdx.x >> 4;
    bool bumped = false;
    unsigned a = __hip_atomic_fetch_add(&P.cnts[grp*16], 1u, __ATOMIC_ACQ_REL, __HIP_MEMORY_SCOPE_AGENT) + 1u;
    if (a == 16u){
      __hip_atomic_store(&P.cnts[grp*16], 0u, __ATOMIC_RELAXED, __HIP_MEMORY_SCOPE_AGENT);
      unsigned s = __hip_atomic_fetch_add(P.sup, 1u, __ATOMIC_ACQ_REL, __HIP_MEMORY_SCOPE_AGENT) + 1u;
      if (s == 16u){
        __hip_atomic_store(P.sup, 0u, __ATOMIC_RELAXED, __HIP_MEMORY_SCOPE_AGENT);
        __hip_atomic_fetch_add(P.gen, 1u, __ATOMIC_RELEASE, __HIP_MEMORY_SCOPE_AGENT);
        bumped = true;
      }
    }
    if (!bumped){
      while (__hip_atomic_load(P.gen, __ATOMIC_ACQUIRE, __HIP_MEMORY_SCOPE_AGENT) == g)
        __builtin_amdgcn_s_sleep(2);
    }
  }
  __syncthreads();
}

// -------- GEMM core: out[c][b] += sum_k act[k][b] * wL[c][k] --------
template<int NCOLS, int KGW>
__device__ __forceinline__ void mm_core(const float* seg0, const float* seg1, const float* seg2,
                                        const float* wL, float* zb, int lane, int wv){
  float acc[NCOLS];
  #pragma unroll
  for (int c=0;c<NCOLS;++c) acc[c]=0.f;
  const int kg0 = wv*KGW;
  #pragma unroll 4
  for (int i=0;i<KGW;++i){
    const int kg = kg0 + i;
    const float* bp = (kg<128) ? seg0 : ((kg<256) ? seg1 : seg2);
    f32x4 a = *(const f32x4*)(bp + ((size_t)kg<<8) + (lane<<2));
    #pragma unroll
    for (int c=0;c<NCOLS;++c){
      f32x4 w = *(const f32x4*)(wL + c*(KGW*64) + (kg<<2));
      acc[c] = fmaf(a[0],w[0],acc[c]); acc[c] = fmaf(a[1],w[1],acc[c]);
      acc[c] = fmaf(a[2],w[2],acc[c]); acc[c] = fmaf(a[3],w[3],acc[c]);
    }
  }
  #pragma unroll
  for (int c=0;c<NCOLS;++c) zb[(wv*NCOLS+c)*64 + lane] = acc[c];
}

// -------- phases A/B: LSTM layers --------
template<int PHASE>
__device__ __forceinline__ void lstm_phase(const Params& P, int t, int rp, float* smem){
  const int wg=blockIdx.x, tid=threadIdx.x, lane=tid&63, wv=tid>>6;
  const float* h1r = rp ? P.h1b : P.h1a;
  float*       h1w = rp ? P.h1a : P.h1b;
  const float* h2r = rp ? P.h2b : P.h2a;
  float*       h2w = rp ? P.h2a : P.h2b;

  if (PHASE==1){
    const float* seg0 = P.tgtT4 + ((size_t)t<<15);
    const float* seg1 = P.attnT4 - 32768;
    const float* seg2 = h1r - 65536;
    mm_core<8,24>(seg0, seg1, seg2, smem+OFF_W1, smem+OFF_ZB, lane, wv);
  } else {
    const float* seg0 = h1w;               // h1 NEW
    const float* seg1 = h2r - 32768;       // h2 old
    mm_core<8,16>(seg0, seg1, seg1, smem+OFF_W2, smem+OFF_ZB, lane, wv);
  }
  __syncthreads();
  if (tid < 512){
    const int gc = tid>>6, b = tid&63;
    const float* zb = smem+OFF_ZB;
    float s = 0.f;
    #pragma unroll
    for (int w=0; w<16; ++w) s += zb[(w*8+gc)*64 + b];
    smem[OFF_ZS + gc*64 + b] = s;
  }
  __syncthreads();
  if (tid < 128){
    const int b = tid&63, j = tid>>6;
    const int h = (wg<<1)+j;
    const float* bias = (PHASE==1) ? P.b1 : P.b2;
    float z[4];
    #pragma unroll
    for (int g=0; g<4; ++g) z[g] = smem[OFF_ZS + (g*2+j)*64 + b] + bias[(g<<9)+h];
    float* cb = (PHASE==1) ? P.c1 : P.c2;
    float* hw = (PHASE==1) ? h1w  : h2w;
    const int ci = (b<<9)+h;
    float co = cb[ci];
    float cn = sigmf(z[1])*co + sigmf(z[0])*tanhf(z[2]);   // i,f,j,o
    float hn = sigmf(z[3])*tanhf(cn);
    cb[ci] = cn;
    hw[((h>>2)<<8) + (b<<2) + (h&3)] = hn;
  }
}

// -------- phase C: q = h2new @ Wm^T --------
__device__ __forceinline__ void qproj_phase(const Params& P, int rp, float* smem){
  const int wg=blockIdx.x, tid=threadIdx.x, lane=tid&63, wv=tid>>6;
  const float* h2n = rp ? P.h2a : P.h2b;
  mm_core<4,8>(h2n, h2n, h2n, smem+OFF_WM, smem+OFF_ZB, lane, wv);
  __syncthreads();
  if (tid < 256){
    const int b = tid&63, j = tid>>6;
    const float* zb = smem+OFF_ZB;
    float s = 0.f;
    #pragma unroll
    for (int w=0; w<16; ++w) s += zb[(w*4+j)*64 + b];
    P.q[(b<<10) + (wg<<2) + j] = s;
  }
}

// -------- enc row fragment (16 floats/lane) --------
struct Row { f32x4 v[4]; };
__device__ __forceinline__ Row load_row(const float* ep, int r){
  Row c;
  const float* p = ep + ((size_t)r<<10);
  c.v[0]=*(const f32x4*)p;     c.v[1]=*(const f32x4*)(p+4);
  c.v[2]=*(const f32x4*)(p+8); c.v[3]=*(const f32x4*)(p+12);
  return c;
}

// -------- phase D: mask-skip streaming flash attention --------
__device__ __forceinline__ void attn_phase(const Params& P, int b, int sg,
                                           const float* ep, unsigned pk, int nact,
                                           Row cur, float* smem){
  const int tid=threadIdx.x, lane=tid&63, wv=tid>>6;
  float* zb = smem + OFF_ZB;    // [8][1024] partial ctx
  float* ml = smem + OFF_ML;    // [16][2]
  const float* qp = P.q + (b<<10) + (lane<<4);
  f32x4 qv0=*(const f32x4*)qp,     qv1=*(const f32x4*)(qp+4),
        qv2=*(const f32x4*)(qp+8), qv3=*(const f32x4*)(qp+12);
  float m=-1e30f, l=0.f;
  f32x4 cx0={0,0,0,0}, cx1={0,0,0,0}, cx2={0,0,0,0}, cx3={0,0,0,0};
  #pragma clang loop unroll(disable)
  for (int i=0;i<nact;++i){
    Row nxt;
    if (i+1<nact) nxt = load_row(ep, (pk>>(4*(i+1)))&15);
    float d=0.f;
    #pragma unroll
    for (int j=0;j<4;++j){
      d=fmaf(cur.v[0][j],qv0[j],d); d=fmaf(cur.v[1][j],qv1[j],d);
      d=fmaf(cur.v[2][j],qv2[j],d); d=fmaf(cur.v[3][j],qv3[j],d);
    }
    d += __shfl_xor(d,1,64);  d += __shfl_xor(d,2,64);  d += __shfl_xor(d,4,64);
    d += __shfl_xor(d,8,64);  d += __shfl_xor(d,16,64); d += __shfl_xor(d,32,64);
    float mn = fmaxf(m, d);
    float fs = __expf(m - mn), e_ = __expf(d - mn);
    l = l*fs + e_;
    cx0 = cx0*fs + cur.v[0]*e_;  cx1 = cx1*fs + cur.v[1]*e_;
    cx2 = cx2*fs + cur.v[2]*e_;  cx3 = cx3*fs + cur.v[3]*e_;
    m = mn;
    cur = nxt;
  }
  if (wv < 8){
    float* cp = zb + (wv<<10) + (lane<<4);
    *(f32x4*)cp = cx0; *(f32x4*)(cp+4)=cx1; *(f32x4*)(cp+8)=cx2; *(f32x4*)(cp+12)=cx3;
  }
  if (lane==0){ ml[wv*2]=m; ml[wv*2+1]=l; }
  __syncthreads();
  if (wv >= 8){
    float M = -1e30f;
    #pragma unroll
    for (int w=0;w<16;++w) M = fmaxf(M, ml[w*2]);
    const float ewj = __expf(ml[(wv-8)*2]-M);
    const float ewo = __expf(ml[wv*2]-M);
    float* cp = zb + ((wv-8)<<10) + (lane<<4);
    f32x4 r0=*(f32x4*)cp, r1=*(f32x4*)(cp+4), r2=*(f32x4*)(cp+8), r3=*(f32x4*)(cp+12);
    r0 = r0*ewj + cx0*ewo;  r1 = r1*ewj + cx1*ewo;
    r2 = r2*ewj + cx2*ewo;  r3 = r3*ewj + cx3*ewo;
    *(f32x4*)cp = r0; *(f32x4*)(cp+4)=r1; *(f32x4*)(cp+8)=r2; *(f32x4*)(cp+12)=r3;
    if (wv==8 && lane==0){
      float L = 0.f;
      #pragma unroll
      for (int w=0;w<16;++w) L += __expf(ml[w*2]-M)*ml[w*2+1];
      P.part_ml[b*8 + sg*2]   = M;
      P.part_ml[b*8 + sg*2+1] = L;
    }
  }
  __syncthreads();
  float c = 0.f;
  #pragma unroll
  for (int j=0;j<8;++j) c += zb[(j<<10)+tid];
  P.part_ctx[((size_t)sg<<16) + ((tid>>2)<<8) + (b<<2) + (tid&3)] = c;
}

// -------- phase E: attn = [h2new, ctx] @ Wa; ctx combined inline --------
__device__ __forceinline__ void out_phase(const Params& P, int t, int rp, float* smem){
  const int wg=blockIdx.x, tid=threadIdx.x, lane=tid&63, wv=tid>>6;
  const float* h2n = rp ? P.h2a : P.h2b;
  f32x4 mlv0 = *(const f32x4*)(P.part_ml + lane*8);
  f32x4 mlv1 = *(const f32x4*)(P.part_ml + lane*8 + 4);
  float M0=mlv0[0], L0=mlv0[1], M1=mlv0[2], L1=mlv0[3];
  float M2=mlv1[0], L2=mlv1[1], M3=mlv1[2], L3=mlv1[3];
  float M = fmaxf(fmaxf(M0,M1), fmaxf(M2,M3));
  float w0=__expf(M0-M), w1=__expf(M1-M), w2=__expf(M2-M), w3=__expf(M3-M);
  float inv = 1.f/(w0*L0 + w1*L1 + w2*L2 + w3*L3);
  w0*=inv; w1*=inv; w2*=inv; w3*=inv;

  const float* wL = smem + OFF_WA;
  float* zb = smem + OFF_ZB;
  float acc0=0.f, acc1=0.f;
  const int kg0 = wv*24;
  #pragma unroll 4
  for (int i=0;i<24;++i){
    const int kg = kg0 + i;
    f32x4 a;
    if (kg < 128){
      a = *(const f32x4*)(h2n + ((size_t)kg<<8) + (lane<<2));
    } else {
      const float* pc = P.part_ctx + (((size_t)kg-128)<<8) + (lane<<2);
      f32x4 g0 = *(const f32x4*)pc;
      f32x4 g1 = *(const f32x4*)(pc + 65536);
      f32x4 g2 = *(const f32x4*)(pc + 131072);
      f32x4 g3 = *(const f32x4*)(pc + 196608);
      #pragma unroll
      for (int j=0;j<4;++j) a[j] = w0*g0[j] + w1*g1[j] + w2*g2[j] + w3*g3[j];
    }
    f32x4 u0 = *(const f32x4*)(wL + 0*1536 + (kg<<2));
    f32x4 u1 = *(const f32x4*)(wL + 1*1536 + (kg<<2));
    acc0 = fmaf(a[0],u0[0],acc0); acc0 = fmaf(a[1],u0[1],acc0);
    acc0 = fmaf(a[2],u0[2],acc0); acc0 = fmaf(a[3],u0[3],acc0);
    acc1 = fmaf(a[0],u1[0],acc1); acc1 = fmaf(a[1],u1[1],acc1);
    acc1 = fmaf(a[2],u1[2],acc1); acc1 = fmaf(a[3],u1[3],acc1);
  }
  zb[(wv*2+0)*64 + lane] = acc0;
  zb[(wv*2+1)*64 + lane] = acc1;
  __syncthreads();
  if (tid < 128){
    const int b = tid&63, j = tid>>6;
    float s = 0.f;
    #pragma unroll
    for (int w=0;w<16;++w) s += zb[(w*2+j)*64 + b];
    const int n = (wg<<1)+j;
    P.out[(((size_t)b<<8) + t)*512 + n] = s;
    P.attnT4[((n>>2)<<8) + (b<<2) + (n&3)] = s;
  }
}

// -------- one-time: weights -> LDS --------
__device__ void load_weights(const Params& P, float* smem){
  const int wg=blockIdx.x, tid=threadIdx.x;
  #pragma unroll
  for (int c=0;c<8;++c){
    const int n = ((c>>1)<<9) + (wg<<1) + (c&1);
    const float* src = P.W1T + (size_t)n*1536;
    float* dst = smem + OFF_W1 + c*1536;
    for (int i=tid;i<1536;i+=NTHR) dst[i]=src[i];
  }
  #pragma unroll
  for (int c=0;c<8;++c){
    const int n = ((c>>1)<<9) + (wg<<1) + (c&1);
    const float* src = P.W2T + (size_t)n*1024;
    float* dst = smem + OFF_W2 + c*1024;
    for (int i=tid;i<1024;i+=NTHR) dst[i]=src[i];
  }
  #pragma unroll
  for (int c=0;c<4;++c){
    const int n = (wg<<2)+c;
    const float* src = P.Wm + (size_t)n*512;
    float* dst = smem + OFF_WM + c*512;
    for (int i=tid;i<512;i+=NTHR) dst[i]=src[i];
  }
  #pragma unroll
  for (int c=0;c<2;++c){
    const int n = (wg<<1)+c;
    const float* src = P.WaT + (size_t)n*1536;
    float* dst = smem + OFF_WA + c*1536;
    for (int i=tid;i<1536;i+=NTHR) dst[i]=src[i];
  }
  __syncthreads();
}

// -------- main persistent kernel --------
__global__ __launch_bounds__(NTHR, 4) __attribute__((amdgpu_waves_per_eu(4,4)))
void seq_main(Params P){
  __shared__ float smem[SMEM_F];
  load_weights(P, smem);

  const int tid=threadIdx.x, lane=tid&63, wv=tid>>6, wg=blockIdx.x;
  const int db = wg>>2, sg = wg&3;
  const int s0 = (sg<<7) + (wv<<3);
  const float* ep = P.enc + ((((size_t)db<<9) + s0)<<10) + (lane<<4);
  // per-wave compacted unmasked-row list (mask==0 -> active); wave-uniform
  unsigned pk = 0; int nact = 0;
  for (int r=0;r<8;++r){
    if (P.mask[(db<<9) + s0 + r] == 0.f){ pk |= (unsigned)r << (4*nact); ++nact; }
  }

  #pragma clang loop unroll(disable)
  for (int t=0; t<256; ++t){
    const int rp = t&1;
    lstm_phase<1>(P, t, rp, smem);   gbar(P);
    lstm_phase<2>(P, t, rp, smem);   gbar(P);
    qproj_phase(P, rp, smem);
    Row cur = load_row(ep, pk & 15);        // issue before barrier: latency hides
    gbar(P);
    attn_phase(P, db, sg, ep, pk, nact, cur, smem);
    gbar(P);
    out_phase(P, t, rp, smem);       gbar(P);
  }
}

// ======== prep kernels ========
__global__ void transT(const float* a, const float* bsrc, float* dst, int K, int N, int KA){
  __shared__ float tile[32][33];
  const int ntk = K>>5;
  const int tn = blockIdx.x / ntk, tk = blockIdx.x - tn*ntk;
  const int tid = threadIdx.x;
  const int c = tid & 31, r = tid >> 5;
  for (int rr=r; rr<32; rr+=8){
    const int k = (tk<<5)+rr, n = (tn<<5)+c;
    tile[rr][c] = (k<KA) ? a[(size_t)k*N+n] : bsrc[(size_t)(k-KA)*N+n];
  }
  __syncthreads();
  for (int rr=r; rr<32; rr+=8){
    const int n = (tn<<5)+rr, k = (tk<<5)+c;
    dst[(size_t)n*K + k] = tile[c][rr];
  }
}

__global__ void prep_tgt(const float* tgt, float* tgtT4){
  __shared__ float xt[64*517];
  const int t = blockIdx.x, tid = threadIdx.x;   // 256 threads
  for (int i=tid; i<64*512; i+=256){
    const int bb = i>>9, k = i&511;
    xt[bb*517 + k] = tgt[((size_t)bb*256 + t)*512 + k];
  }
  __syncthreads();
  for (int i=tid; i<128*64; i+=256){
    const int kg = i>>6, bb = i&63;
    f32x4 v = { xt[bb*517 + kg*4], xt[bb*517 + kg*4 + 1],
                xt[bb*517 + kg*4 + 2], xt[bb*517 + kg*4 + 3] };
    *(f32x4*)(tgtT4 + ((size_t)t<<15) + (kg<<8) + (bb<<2)) = v;
  }
}

__global__ void init_state(const float* fwh, const float* fwc, const float* bwh, const float* bwc,
                           float* h1a, float* h2a, float* attnT4, float* c1, float* c2,
                           unsigned* cnts, unsigned* sup, unsigned* gen){
  const int i = blockIdx.x*blockDim.x + threadIdx.x;
  if (i < 64*512){
    const int bb = i>>9, k = i&511;
    const int t4 = ((k>>2)<<8) + (bb<<2) + (k&3);
    h1a[t4] = fwh[i];
    h2a[t4] = bwh[i];
    attnT4[t4] = 0.f;
    c1[i] = fwc[i];
    c2[i] = bwc[i];
  }
  if (i < 16) cnts[i*16] = 0u;
  if (i == 16){ *sup = 0u; }
  if (i == 17){ *gen = 0u; }
}

extern "C" void kernel_launch(void* const* d_in, const int* in_sizes, int n_in,
                              void* d_out, int out_size, void* d_ws, size_t ws_size,
                              hipStream_t stream){
  if (n_in < 15) return;
  const float* tgt = (const float*)d_in[0];
  const float* fwh = (const float*)d_in[1];
  const float* fwc = (const float*)d_in[2];
  const float* bwh = (const float*)d_in[3];
  const float* bwc = (const float*)d_in[4];
  const float* enc = (const float*)d_in[5];
  const float* msk = (const float*)d_in[6];
  const float* Wm  = (const float*)d_in[7];
  const float* Wa  = (const float*)d_in[8];
  const float* ki1 = (const float*)d_in[9];
  const float* kr1 = (const float*)d_in[10];
  const float* b1  = (const float*)d_in[11];
  const float* ki2 = (const float*)d_in[12];
  const float* kr2 = (const float*)d_in[13];
  const float* b2  = (const float*)d_in[14];

  char* w = (char*)d_ws;
  size_t o = 0;
  auto carve = [&](size_t bytes)->char*{
    char* r = w + o; o = (o + bytes + 255) & ~(size_t)255; return r;
  };
  float* W1T    = (float*)carve(2048ull*1536*4);
  float* W2T    = (float*)carve(2048ull*1024*4);
  float* WaT    = (float*)carve(512ull*1536*4);
  float* tgtT4  = (float*)carve(256ull*128*256*4);
  float* h1a    = (float*)carve(128ull*256*4);
  float* h1b    = (float*)carve(128ull*256*4);
  float* h2a    = (float*)carve(128ull*256*4);
  float* h2b    = (float*)carve(128ull*256*4);
  float* attnT4 = (float*)carve(128ull*256*4);
  float* q      = (float*)carve(64ull*1024*4);
  float* c1     = (float*)carve(64ull*512*4);
  float* c2     = (float*)carve(64ull*512*4);
  float* part_ctx = (float*)carve(4ull*256*256*4);
  float* part_ml  = (float*)carve(64ull*8*4);
  unsigned* cnts = (unsigned*)carve(16*64);
  unsigned* sup  = (unsigned*)carve(128);
  unsigned* gen  = (unsigned*)carve(128);
  if (o > ws_size) return;   // ~61 MB needed

  hipLaunchKernelGGL(transT, dim3(64*48), dim3(256), 0, stream, ki1, kr1, W1T, 1536, 2048, 1024);
  hipLaunchKernelGGL(transT, dim3(64*32), dim3(256), 0, stream, ki2, kr2, W2T, 1024, 2048, 512);
  hipLaunchKernelGGL(transT, dim3(16*48), dim3(256), 0, stream, Wa,  Wa,  WaT, 1536, 512, 1536);
  hipLaunchKernelGGL(prep_tgt, dim3(256), dim3(256), 0, stream, tgt, tgtT4);
  hipLaunchKernelGGL(init_state, dim3(128), dim3(256), 0, stream,
                     fwh, fwc, bwh, bwc, h1a, h2a, attnT4, c1, c2, cnts, sup, gen);

  Params P;
  P.tgtT4 = tgtT4; P.mask = msk; P.b1 = b1; P.b2 = b2;
  P.Wm = Wm; P.enc = enc;
  P.W1T = W1T; P.W2T = W2T; P.WaT = WaT;
  P.h1a = h1a; P.h1b = h1b; P.h2a = h2a; P.h2b = h2b;
  P.attnT4 = attnT4; P.q = q;
  P.c1 = c1; P.c2 = c2;
  P.part_ctx = part_ctx; P.part_ml = part_ml;
  P.cnts = cnts; P.sup = sup; P.gen = gen;
  P.out = (float*)d_out;

  hipLaunchKernelGGL(seq_main, dim3(NWG), dim3(NTHR), 0, stream, P);
}